// Round 5
// baseline (921.368 us; speedup 1.0000x reference)
//
#include <hip/hip_runtime.h>
#include <hip/hip_bf16.h>
#include <hip/hip_fp16.h>
#include <math.h>

#define N_NODES 50000
#define NP      50048          // padded node count (multiple of 64)
#define SEQ     16
#define FIN     64
#define HID     128
#define NEDGE   1600000

// merged kernel-1 grid layout (512-thread blocks)
#define NB_PREP  32                    // 32*512 = 16384 = 128*128
#define NB_COUNT 3125                  // 3125*512 = 1.6M
#define NB_GRU   (NP / 32)             // 1564
#define K1_GRID  (NB_PREP + NB_COUNT + NB_GRU)

// merged kernel-3 grid layout (256-thread blocks)
#define NB_PROJ  (NP / 32)             // 1564
#define NB_FILL  6250                  // 6250*256 = 1.6M
#define K3_GRID  (NB_PROJ + NB_FILL)

typedef __attribute__((ext_vector_type(8))) short short8;   // 8 bf16 = 4 VGPRs
typedef __attribute__((ext_vector_type(4))) float f32x4;

__device__ __forceinline__ float lrelu02(float v) { return v > 0.f ? v : 0.2f * v; }
__device__ __forceinline__ float frcp(float v) { return __builtin_amdgcn_rcpf(v); }
__device__ __forceinline__ float sigmoidf_(float v) { return frcp(1.f + __expf(-v)); }
__device__ __forceinline__ float eluf_(float v) { return v > 0.f ? v : (__expf(v) - 1.f); }
__device__ __forceinline__ f32x4 mk4(float v) { f32x4 r; r[0] = v; r[1] = v; r[2] = v; r[3] = v; return r; }

// packed fp32x2 -> bf16x2 (v_cvt_pk_bf16_f32 on gfx950), RNE
__device__ __forceinline__ unsigned bfpk(float lo, float hi) {
    union { __hip_bfloat162 h; unsigned u; } c;
    c.h = __float22bfloat162_rn(make_float2(lo, hi));
    return c.u;
}
// packed fp32x2 -> fp16x2
__device__ __forceinline__ unsigned hfpk(float lo, float hi) {
    union { __half2 h; unsigned u; } c;
    c.h = __float22half2_rn(make_float2(lo, hi));
    return c.u;
}
__device__ __forceinline__ float2 h2f2(unsigned u) {
    union { unsigned u; __half2 h; } c;
    c.u = u;
    return __half22float2(c.h);
}
__device__ __forceinline__ short8 pack8(float4 a, float4 b) {
    union { short8 s; unsigned u[4]; } r;
    r.u[0] = bfpk(a.x, a.y); r.u[1] = bfpk(a.z, a.w);
    r.u[2] = bfpk(b.x, b.y); r.u[3] = bfpk(b.z, b.w);
    return r.s;
}

// ---------------------------------------------------------------------------
// GRU device body: one block = 32 nodes, all 16 timesteps. 512 threads = 8
// waves; wave w owns ch slice [16w,16w+16) of all three gates. Gate math is
// register-only (MFMA C-layout puts r,z,i_n,h_n of a (node,ch) in one lane).
// Biases folded into MFMA accumulator init. 1 barrier/step.
// ---------------------------------------------------------------------------
__device__ void gru_body(
    int bid,
    const float* __restrict__ x, const float* __restrict__ w_ih,
    const float* __restrict__ w_hh, const float* __restrict__ b_ih,
    const float* __restrict__ b_hh, float* __restrict__ hout)
{
    // row stride 72 shorts = 144 B (16-aligned for ds_read_b128)
    __shared__ __align__(16) short hA[2][32][72];
    __shared__ __align__(16) short xB[2][32][72];

    const int tid  = threadIdx.x;
    const int wave = tid >> 6;
    const int lane = tid & 63;
    const int q    = lane >> 4;      // quad 0..3
    const int rl   = lane & 15;
    const int n0   = bid * 32;
    const int ch   = wave * 16 + rl; // channel within gate

    // resident weight B-fragments (bf16): 3 gates x this ch-slice
    short8 whhf[3][4];   // [gate][kc] K=128
    short8 wihf[3][2];   // [gate][kc] K=64
#pragma unroll
    for (int g = 0; g < 3; g++) {
        int row = g * 128 + ch;
#pragma unroll
        for (int kc = 0; kc < 4; kc++) {
            const float* p = w_hh + row * HID + kc * 32 + q * 8;
            whhf[g][kc] = pack8(*(const float4*)p, *(const float4*)(p + 4));
        }
#pragma unroll
        for (int kc = 0; kc < 2; kc++) {
            const float* p = w_ih + row * FIN + kc * 32 + q * 8;
            wihf[g][kc] = pack8(*(const float4*)p, *(const float4*)(p + 4));
        }
    }

    // per-lane biases (folded into accumulator init below)
    const float br  = b_ih[ch] + b_hh[ch];
    const float bz  = b_ih[128 + ch] + b_hh[128 + ch];
    const float bin = b_ih[256 + ch];
    const float bhn = b_hh[256 + ch];

    // staging: thread owns 4 consecutive floats of the 32x64 x-tile
    const int sn = tid >> 4;          // node 0..31
    const int sk = (tid & 15) * 4;    // k 0..60
    int sgn = n0 + sn; if (sgn > N_NODES - 1) sgn = N_NODES - 1;
    const float* xsp = x + (size_t)sgn * SEQ * FIN + sk;

    float hreg[2][4];
#pragma unroll
    for (int mt = 0; mt < 2; mt++)
#pragma unroll
        for (int r = 0; r < 4; r++) hreg[mt][r] = 0.f;

    // stage x(t=0)
    {
        float4 v = *(const float4*)(xsp);
        int2 pv;
        pv.x = (int)bfpk(v.x, v.y);
        pv.y = (int)bfpk(v.z, v.w);
        *(int2*)&xB[0][sn][sk] = pv;
    }
    __syncthreads();

    for (int t = 0; t < SEQ; t++) {
        const int xb = t & 1;
        short8 xf[2][2], hf[2][4];
#pragma unroll
        for (int mt = 0; mt < 2; mt++)
#pragma unroll
            for (int kc = 0; kc < 2; kc++)
                xf[mt][kc] = *(const short8*)&xB[xb][mt * 16 + rl][kc * 32 + q * 8];
        if (t > 0) {
            const int hb = (t - 1) & 1;
#pragma unroll
            for (int mt = 0; mt < 2; mt++)
#pragma unroll
                for (int kc = 0; kc < 4; kc++)
                    hf[mt][kc] = *(const short8*)&hA[hb][mt * 16 + rl][kc * 32 + q * 8];
        }

        // issue next-step x load early
        float4 xs;
        if (t + 1 < SEQ) xs = *(const float4*)(xsp + (t + 1) * FIN);

        // MFMAs (biases pre-loaded into accumulators)
        f32x4 accr[2], accz[2], accin[2], acchn[2];
#pragma unroll
        for (int mt = 0; mt < 2; mt++) {
            accr[mt] = mk4(br); accz[mt] = mk4(bz);
            accin[mt] = mk4(bin); acchn[mt] = mk4(bhn);
#pragma unroll
            for (int kc = 0; kc < 2; kc++) {
                accr[mt]  = __builtin_amdgcn_mfma_f32_16x16x32_bf16(xf[mt][kc], wihf[0][kc], accr[mt], 0, 0, 0);
                accz[mt]  = __builtin_amdgcn_mfma_f32_16x16x32_bf16(xf[mt][kc], wihf[1][kc], accz[mt], 0, 0, 0);
                accin[mt] = __builtin_amdgcn_mfma_f32_16x16x32_bf16(xf[mt][kc], wihf[2][kc], accin[mt], 0, 0, 0);
            }
            if (t > 0) {
#pragma unroll
                for (int kc = 0; kc < 4; kc++) {
                    accr[mt]  = __builtin_amdgcn_mfma_f32_16x16x32_bf16(hf[mt][kc], whhf[0][kc], accr[mt], 0, 0, 0);
                    accz[mt]  = __builtin_amdgcn_mfma_f32_16x16x32_bf16(hf[mt][kc], whhf[1][kc], accz[mt], 0, 0, 0);
                    acchn[mt] = __builtin_amdgcn_mfma_f32_16x16x32_bf16(hf[mt][kc], whhf[2][kc], acchn[mt], 0, 0, 0);
                }
            }
        }

        // stage x(t+1) into the other buffer
        if (t + 1 < SEQ) {
            int2 pv;
            pv.x = (int)bfpk(xs.x, xs.y);
            pv.y = (int)bfpk(xs.z, xs.w);
            *(int2*)&xB[(t + 1) & 1][sn][sk] = pv;
        }

        // gate math in registers; write new h (bf16) to hA[t&1]
        const int b = t & 1;
#pragma unroll
        for (int mt = 0; mt < 2; mt++) {
            float hv[4];
#pragma unroll
            for (int r = 0; r < 4; r++) {
                float rg = sigmoidf_(accr[mt][r]);
                float zg = sigmoidf_(accz[mt][r]);
                float a  = fmaf(rg, acchn[mt][r], accin[mt][r]);
                float e  = __expf(2.f * a);
                float nn = 1.f - 2.f * frcp(e + 1.f);
                float h  = fmaf(zg, hreg[mt][r] - nn, nn);
                hreg[mt][r] = h;
                hv[r] = h;
            }
            unsigned u01 = bfpk(hv[0], hv[1]);
            unsigned u23 = bfpk(hv[2], hv[3]);
            const int nb = mt * 16 + q * 4;
            hA[b][nb + 0][ch] = (short)(u01 & 0xFFFF);
            hA[b][nb + 1][ch] = (short)(u01 >> 16);
            hA[b][nb + 2][ch] = (short)(u23 & 0xFFFF);
            hA[b][nb + 3][ch] = (short)(u23 >> 16);
        }
        __syncthreads();
    }

#pragma unroll
    for (int mt = 0; mt < 2; mt++)
#pragma unroll
        for (int r = 0; r < 4; r++)
            hout[(size_t)(n0 + mt * 16 + q * 4 + r) * HID + ch] = hreg[mt][r];
}

// ---------------------------------------------------------------------------
// Kernel 1: prep (GAT weight transpose) + edge count + GRU, one launch.
// Block ranges: [0,32) prep, [32, 32+3125) count, rest GRU.
// ---------------------------------------------------------------------------
__global__ __launch_bounds__(512, 2) void k1_prep_count_gru(
    const float* __restrict__ x, const float* __restrict__ w_ih,
    const float* __restrict__ w_hh, const float* __restrict__ b_ih,
    const float* __restrict__ b_hh, float* __restrict__ hout,
    const float* __restrict__ g1w, const float* __restrict__ g2w,
    float* __restrict__ g1T, float* __restrict__ g2T,
    const int* __restrict__ dst, int* __restrict__ deg)
{
    const int gb = blockIdx.x;
    if (gb < NB_PREP) {
        int i = gb * 512 + threadIdx.x;      // [0, 16384)
        int k = i >> 7, g = i & 127;
        g1T[i] = g1w[g * 128 + k];
        g2T[i] = g2w[g * 128 + k];
        return;
    }
    if (gb < NB_PREP + NB_COUNT) {
        int i = (gb - NB_PREP) * 512 + threadIdx.x;
        if (i < NEDGE) atomicAdd(&deg[dst[i]], 1);
        return;
    }
    gru_body(gb - NB_PREP - NB_COUNT, x, w_ih, w_hh, b_ih, b_hh, hout);
}

// ---------------------------------------------------------------------------
// Kernel 2: exclusive-scan of deg into rp, single 1024-thread block.
// ---------------------------------------------------------------------------
__global__ __launch_bounds__(1024) void scan_kernel(const int* __restrict__ deg,
                                                    int* __restrict__ rp)
{
    __shared__ int ws[16];
    __shared__ int carry;
    const int tid = threadIdx.x, lane = tid & 63, w = tid >> 6;
    if (tid == 0) { carry = 0; rp[0] = 0; }
    __syncthreads();
    for (int base = 0; base < N_NODES; base += 1024) {
        int i = base + tid;
        int v = (i < N_NODES) ? deg[i] : 0;
        int sv = v;
#pragma unroll
        for (int off = 1; off < 64; off <<= 1) {
            int tmp = __shfl_up(sv, off, 64);
            if (lane >= off) sv += tmp;
        }
        if (lane == 63) ws[w] = sv;
        __syncthreads();
        int add = 0, total = 0;
#pragma unroll
        for (int k = 0; k < 16; k++) {
            int s = ws[k];
            if (k < w) add += s;
            total += s;
        }
        int incl = sv + add + carry;
        if (i < N_NODES) rp[i + 1] = incl;
        __syncthreads();
        if (tid == 0) carry += total;
        __syncthreads();
    }
}

// ---------------------------------------------------------------------------
// GAT projection + attention coefficients (device body). 32 nodes/block,
// 256 threads. Writes fp16-packed features + per-(node,head) dots.
// ---------------------------------------------------------------------------
__device__ void proj_attn_body(
    int bid, const float* __restrict__ x, const float* __restrict__ wT,
    const float* __restrict__ a_src, const float* __restrict__ a_dst,
    unsigned* __restrict__ hph, float* __restrict__ as_, float* __restrict__ ad_)
{
    __shared__ float xt[32][33];
    __shared__ float wt[32][128];
    __shared__ float ot[32][132];
    const int tid = threadIdx.x;
    const int tx = tid & 7;       // 8 node groups of 4
    const int ty = tid >> 3;      // 32 out groups of 4
    const int n0 = bid * 32;
    float acc[4][4];
#pragma unroll
    for (int i = 0; i < 4; i++)
#pragma unroll
        for (int j = 0; j < 4; j++) acc[i][j] = 0.f;

    for (int k0 = 0; k0 < 128; k0 += 32) {
        __syncthreads();
#pragma unroll
        for (int i = 0; i < 4; i++) {
            int flat = tid + i * 256;
            int n = flat >> 5, k = flat & 31;
            xt[n][k] = x[(n0 + n) * HID + k0 + k];
        }
#pragma unroll
        for (int i = 0; i < 16; i++) {
            int flat = tid + i * 256;
            int kk = flat >> 7, g = flat & 127;
            wt[kk][g] = wT[(k0 + kk) * HID + g];
        }
        __syncthreads();
#pragma unroll 8
        for (int kk = 0; kk < 32; kk++) {
            float xv[4];
#pragma unroll
            for (int i = 0; i < 4; i++) xv[i] = xt[tx * 4 + i][kk];
            float4 wv = *(const float4*)&wt[kk][ty * 4];
#pragma unroll
            for (int i = 0; i < 4; i++) {
                acc[i][0] = fmaf(xv[i], wv.x, acc[i][0]);
                acc[i][1] = fmaf(xv[i], wv.y, acc[i][1]);
                acc[i][2] = fmaf(xv[i], wv.z, acc[i][2]);
                acc[i][3] = fmaf(xv[i], wv.w, acc[i][3]);
            }
        }
    }
#pragma unroll
    for (int i = 0; i < 4; i++) {
        int node = tx * 4 + i;
        ot[node][ty * 4 + 0] = acc[i][0];
        ot[node][ty * 4 + 1] = acc[i][1];
        ot[node][ty * 4 + 2] = acc[i][2];
        ot[node][ty * 4 + 3] = acc[i][3];
        uint2 pv;
        pv.x = hfpk(acc[i][0], acc[i][1]);
        pv.y = hfpk(acc[i][2], acc[i][3]);
        *(uint2*)&hph[(size_t)(n0 + node) * 64 + ty * 2] = pv;
    }
    __syncthreads();
    if (tid < 128) {
        int node = tid >> 2, head = tid & 3;
        const float* ar = a_src + head * 32;
        const float* br = a_dst + head * 32;
        float s = 0.f, d = 0.f;
#pragma unroll
        for (int j = 0; j < 32; j += 4) {
            float4 hv = *(const float4*)&ot[node][head * 32 + j];
            float4 av = *(const float4*)&ar[j];
            float4 bv = *(const float4*)&br[j];
            s += hv.x * av.x + hv.y * av.y + hv.z * av.z + hv.w * av.w;
            d += hv.x * bv.x + hv.y * bv.y + hv.z * bv.z + hv.w * bv.w;
        }
        as_[(n0 + node) * 4 + head] = s;
        ad_[(n0 + node) * 4 + head] = d;
    }
}

// ---------------------------------------------------------------------------
// Kernel 3: proj_attn(layer1) + fill_edges, one launch (256-thread blocks).
// ---------------------------------------------------------------------------
__global__ __launch_bounds__(256) void k3_proj_fill(
    const float* __restrict__ xin, const float* __restrict__ wT,
    const float* __restrict__ a_src, const float* __restrict__ a_dst,
    unsigned* __restrict__ hph, float* __restrict__ as_, float* __restrict__ ad_,
    const int* __restrict__ src, const int* __restrict__ dst,
    const int* __restrict__ rp, int* __restrict__ cur, int* __restrict__ col)
{
    const int gb = blockIdx.x;
    if (gb < NB_PROJ) {
        proj_attn_body(gb, xin, wT, a_src, a_dst, hph, as_, ad_);
        return;
    }
    int i = (gb - NB_PROJ) * 256 + threadIdx.x;
    if (i < NEDGE) {
        int d = dst[i];
        int pos = atomicAdd(&cur[d], 1);
        col[rp[d] + pos] = src[i];
    }
}

// plain proj_attn launch (layer 2)
__global__ __launch_bounds__(256) void proj_attn_kernel(
    const float* __restrict__ xin, const float* __restrict__ wT,
    const float* __restrict__ a_src, const float* __restrict__ a_dst,
    unsigned* __restrict__ hph, float* __restrict__ as_, float* __restrict__ ad_)
{
    proj_attn_body(blockIdx.x, xin, wT, a_src, a_dst, hph, as_, ad_);
}

// ---------------------------------------------------------------------------
// GAT aggregation, SINGLE PASS: denom accumulated alongside the weighted sum
// (no softmax shift needed: logits are O(8), fp32 exp safe — validated R3/R4).
// One wave per dst node; lane owns channel pair (2*lane, 2*lane+1).
// CLF: classifier fused (layer-2 features never reach HBM).
// ---------------------------------------------------------------------------
template <bool CLF>
__global__ __launch_bounds__(256) void gat_agg(
    const unsigned* __restrict__ hph, const float* __restrict__ as_,
    const float* __restrict__ ad_, const int* __restrict__ rp,
    const int* __restrict__ col, const float* __restrict__ bias,
    float* __restrict__ out, const float* __restrict__ cw,
    const float* __restrict__ cb, int n_nodes)
{
    const int lane = threadIdx.x & 63;
    const int n = blockIdx.x * 4 + (threadIdx.x >> 6);
    if (n >= n_nodes) return;

    const int e0 = rp[n], e1 = rp[n + 1];
    const int head = lane >> 4;
    float4 adv = *(const float4*)&ad_[n * 4];
    float adh = (head == 0) ? adv.x : (head == 1) ? adv.y : (head == 2) ? adv.z : adv.w;

    // self-loop
    float ws = __expf(lrelu02(as_[n * 4 + head] + adh));
    float2 sv = h2f2(hph[(size_t)n * 64 + lane]);
    float den = ws;
    float acc0 = ws * sv.x;
    float acc1 = ws * sv.y;

    int e = e0;
    for (; e + 4 <= e1; e += 4) {
        int s_[4]; float a_[4]; unsigned u_[4];
#pragma unroll
        for (int u = 0; u < 4; u++) s_[u] = col[e + u];
#pragma unroll
        for (int u = 0; u < 4; u++) {
            a_[u] = as_[s_[u] * 4 + head];
            u_[u] = hph[(size_t)s_[u] * 64 + lane];
        }
#pragma unroll
        for (int u = 0; u < 4; u++) {
            float w = __expf(lrelu02(a_[u] + adh));
            float2 f = h2f2(u_[u]);
            den += w;
            acc0 = fmaf(w, f.x, acc0);
            acc1 = fmaf(w, f.y, acc1);
        }
    }
    for (; e < e1; e++) {
        int s = col[e];
        float w = __expf(lrelu02(as_[s * 4 + head] + adh));
        float2 f = h2f2(hph[(size_t)s * 64 + lane]);
        den += w;
        acc0 = fmaf(w, f.x, acc0);
        acc1 = fmaf(w, f.y, acc1);
    }

    float inv = frcp(den + 1e-16f);
    float2 b2 = *(const float2*)&bias[2 * lane];
    float o0 = eluf_(acc0 * inv + b2.x);
    float o1 = eluf_(acc1 * inv + b2.y);
    if (CLF) {
        float2 cwv = *(const float2*)&cw[2 * lane];
        float v = o0 * cwv.x + o1 * cwv.y;
#pragma unroll
        for (int off = 32; off >= 1; off >>= 1) v += __shfl_xor(v, off, 64);
        if (lane == 0) out[n] = sigmoidf_(v + cb[0]);
    } else {
        *(float2*)&out[(size_t)n * HID + 2 * lane] = make_float2(o0, o1);
    }
}

// ---------------------------------------------------------------------------
extern "C" void kernel_launch(void* const* d_in, const int* in_sizes, int n_in,
                              void* d_out, int out_size, void* d_ws, size_t ws_size,
                              hipStream_t stream)
{
    const float* x     = (const float*)d_in[0];
    const int*   ei    = (const int*)d_in[1];
    const float* w_ih  = (const float*)d_in[2];
    const float* w_hh  = (const float*)d_in[3];
    const float* b_ih  = (const float*)d_in[4];
    const float* b_hh  = (const float*)d_in[5];
    const float* g1w   = (const float*)d_in[6];
    const float* g1as  = (const float*)d_in[7];
    const float* g1ad  = (const float*)d_in[8];
    const float* g1b   = (const float*)d_in[9];
    const float* g2w   = (const float*)d_in[10];
    const float* g2as  = (const float*)d_in[11];
    const float* g2ad  = (const float*)d_in[12];
    const float* g2b   = (const float*)d_in[13];
    const float* cw    = (const float*)d_in[14];
    const float* cb    = (const float*)d_in[15];
    float* out = (float*)d_out;

    char* wsb = (char*)d_ws;
    size_t off = 0;
    auto alc = [&](size_t bytes) { size_t o = off; off += (bytes + 255) & ~(size_t)255; return o; };

    float*    bufA = (float*)(wsb + alc((size_t)NP * HID * 4));      // GRU h
    float*    bufC = (float*)(wsb + alc((size_t)NP * HID * 4));      // layer-1 out
    unsigned* hph  = (unsigned*)(wsb + alc((size_t)NP * 64 * 4));    // fp16-packed features
    float*    as_  = (float*)(wsb + alc((size_t)NP * 4 * 4));
    float*    ad_  = (float*)(wsb + alc((size_t)NP * 4 * 4));
    float*    g1T  = (float*)(wsb + alc((size_t)128 * 128 * 4));
    float*    g2T  = (float*)(wsb + alc((size_t)128 * 128 * 4));
    int*      rp   = (int*)(wsb + alc((size_t)(N_NODES + 1) * 4));
    size_t    degoff = alc((size_t)N_NODES * 4);
    int*      deg  = (int*)(wsb + degoff);
    size_t    curoff = alc((size_t)N_NODES * 4);
    int*      cur  = (int*)(wsb + curoff);
    int*      col  = (int*)(wsb + alc((size_t)NEDGE * 4));

    const int* src = ei;
    const int* dst = ei + NEDGE;

    // zero deg+cur in one shot (they're adjacent in the workspace)
    hipMemsetAsync(deg, 0, curoff + (size_t)N_NODES * 4 - degoff, stream);

    // K1: GAT weight transpose + edge degree count + fused GRU
    k1_prep_count_gru<<<K1_GRID, 512, 0, stream>>>(
        x, w_ih, w_hh, b_ih, b_hh, bufA, g1w, g2w, g1T, g2T, dst, deg);

    // K2: scan deg -> rp (single block)
    scan_kernel<<<1, 1024, 0, stream>>>(deg, rp);

    // K3: layer-1 projection+attention + CSR fill
    k3_proj_fill<<<K3_GRID, 256, 0, stream>>>(
        bufA, g1T, g1as, g1ad, hph, as_, ad_, src, dst, rp, cur, col);

    // K4: layer-1 aggregation
    gat_agg<false><<<(N_NODES + 3) / 4, 256, 0, stream>>>(hph, as_, ad_, rp, col, g1b, bufC,
                                                          nullptr, nullptr, N_NODES);

    // K5: layer-2 projection+attention
    proj_attn_kernel<<<NB_PROJ, 256, 0, stream>>>(bufC, g2T, g2as, g2ad, hph, as_, ad_);

    // K6: layer-2 aggregation + classifier
    gat_agg<true><<<(N_NODES + 3) / 4, 256, 0, stream>>>(hph, as_, ad_, rp, col, g2b, out,
                                                         cw, cb, N_NODES);
}